// Round 1
// baseline (199.425 us; speedup 1.0000x reference)
//
#include <hip/hip_runtime.h>
#include <math.h>

#define XYD 16
#define ZD 16
#define SS 4096
#define VV 2048
#define BB 8
#define LL 32
#define WW 8
#define VC 32   // v-chunk for smoothing kernel

// ---------------- Kernel 1: logZ[s] = logsumexp over V of emis_w[s,:] ----------------
// one wave per row, 4 waves per block, 1024 blocks
__global__ void k_logZ(const float* __restrict__ emis_w, float* __restrict__ logZ) {
    int wave = threadIdx.x >> 6;
    int lane = threadIdx.x & 63;
    int row  = blockIdx.x * 4 + wave;
    const float* r = emis_w + (size_t)row * VV;
    float vals[32];
    float m = -INFINITY;
#pragma unroll
    for (int k = 0; k < 8; k++) {
        float4 f = ((const float4*)r)[k * 64 + lane];
        vals[k*4+0] = f.x; vals[k*4+1] = f.y; vals[k*4+2] = f.z; vals[k*4+3] = f.w;
    }
#pragma unroll
    for (int k = 0; k < 32; k++) m = fmaxf(m, vals[k]);
#pragma unroll
    for (int o = 32; o; o >>= 1) m = fmaxf(m, __shfl_xor(m, o));
    float sum = 0.f;
#pragma unroll
    for (int k = 0; k < 32; k++) sum += __expf(vals[k] - m);
#pragma unroll
    for (int o = 32; o; o >>= 1) sum += __shfl_xor(sum, o);
    if (lane == 0) logZ[row] = m + __logf(sum);
}

// ---------------- Kernel 2: smoothing + transpose ----------------
// smoothedT[v*S + s] = log( 0.2 * sum of 5 neighbor softmax-probs )
// grid (z=16, vchunk=64), 256 threads; LDS tile [256 states][VC+1]
__global__ void k_smooth(const float* __restrict__ emis_w, const float* __restrict__ logZ,
                         float* __restrict__ smT) {
    __shared__ float tile[256 * (VC + 1)];
    int z  = blockIdx.x;
    int v0 = blockIdx.y * VC;
    int tid = threadIdx.x;

    // load phase: 256*VC elements; flat f = i*256+tid; row=f/VC, col=f%VC (coalesced-ish)
#pragma unroll
    for (int i = 0; i < VC; i++) {
        int f = i * 256 + tid;
        int row = f >> 5;        // /VC (VC==32)
        int col = f & 31;        // %VC
        int sg = z * 256 + row;
        float w = emis_w[(size_t)sg * VV + v0 + col];
        tile[row * (VC + 1) + col] = __expf(w - logZ[sg]);
    }
    __syncthreads();

    // compute phase: thread tid handles plane-state s=tid for all VC columns
    int x = tid & 15, y = tid >> 4;
    int sxp = (x < 15) ? tid + 1  : tid;
    int sxm = (x > 0)  ? tid - 1  : tid;
    int syp = (y < 15) ? tid + 16 : tid;
    int sym = (y > 0)  ? tid - 16 : tid;
#pragma unroll
    for (int i = 0; i < VC; i++) {
        float s = tile[tid * (VC + 1) + i] + tile[sxp * (VC + 1) + i] +
                  tile[sxm * (VC + 1) + i] + tile[syp * (VC + 1) + i] +
                  tile[sym * (VC + 1) + i];
        smT[(size_t)(v0 + i) * SS + z * 256 + tid] = __logf(s * 0.2f);
    }
}

// ---------------- Kernel 3: all_emis[t,b,s] = sum_w smoothedT[tok][s] ----------------
// 256 blocks (t*B+b), 256 threads
__global__ void k_emis(const int* __restrict__ stories, const float* __restrict__ smT,
                       float* __restrict__ all_emis) {
    int blk = blockIdx.x;
    int t = blk >> 3, b = blk & 7;
    int tok[WW];
#pragma unroll
    for (int w = 0; w < WW; w++) tok[w] = stories[(b * LL + t) * WW + w];
    int tid = threadIdx.x;
#pragma unroll
    for (int i = 0; i < 16; i++) {
        int s = i * 256 + tid;
        float sum = 0.f;
#pragma unroll
        for (int w = 0; w < WW; w++) {
            int tk = tok[w];
            if (tk < VV) sum += smT[(size_t)tk * SS + s];  // wave-uniform branch
        }
        all_emis[((size_t)t * BB + b) * SS + s] = sum;
    }
}

// ---------------- Kernel 4: transition tables ----------------
// g_dest[j*7+k], g_lw[j*7+k]: valid-compacted dests + log-softmax weights (-inf pad, dest=j)
__global__ void k_trans(const float* __restrict__ trans_w, int* __restrict__ g_dest,
                        float* __restrict__ g_lw) {
    int j = blockIdx.x * 256 + threadIdx.x;
    int zz = j >> 8, rem = j & 255, yy = rem >> 4, xx = rem & 15;
    const int ox[7] = {0, 1, -1, 0, 0, 0, 0};
    const int oy[7] = {0, 0, 0, 1, -1, 0, 0};
    const int oz[7] = {0, 0, 0, 0, 0, 1, 2};
    int dl[7]; int cnt = 0;
    for (int k = 0; k < 7; k++) {
        int nx = xx + ox[k], ny = yy + oy[k], nz = zz + oz[k];
        if (nx >= 0 && nx < XYD && ny >= 0 && ny < XYD && nz >= 0 && nz < ZD)
            dl[cnt++] = nx + XYD * ny + 256 * nz;
    }
    float m = -INFINITY;
    for (int k = 0; k < cnt; k++) m = fmaxf(m, trans_w[j * 7 + k]);
    float se = 0.f;
    for (int k = 0; k < cnt; k++) se += expf(trans_w[j * 7 + k] - m);
    float lse = m + logf(se);
    for (int k = 0; k < 7; k++) {
        if (k < cnt) { g_dest[j * 7 + k] = dl[k]; g_lw[j * 7 + k] = trans_w[j * 7 + k] - lse; }
        else         { g_dest[j * 7 + k] = j;     g_lw[j * 7 + k] = -INFINITY; }
    }
}

// ---------------- Kernel 5: forward recurrence ----------------
// one block per batch b (8 blocks, 1024 threads, 4 states/thread)
__global__ void __launch_bounds__(1024) k_forward(
    const int* __restrict__ g_dest, const float* __restrict__ g_lw,
    const float* __restrict__ prior_w, const float* __restrict__ all_emis,
    float* __restrict__ out) {
    __shared__ float Sbuf[2][SS];
    __shared__ float red[16];
    int b = blockIdx.x;
    int tid = threadIdx.x;
    int lane = tid & 63, wid = tid >> 6;

    // per-thread transition data (constant-indexed register arrays)
    int   dst[4][7];
    float lw[4][7];
#pragma unroll
    for (int q = 0; q < 4; q++) {
        int j = q * 1024 + tid;
#pragma unroll
        for (int k = 0; k < 7; k++) {
            dst[q][k] = g_dest[j * 7 + k];
            lw[q][k]  = g_lw[j * 7 + k];
        }
    }

    // priors = log_softmax(prior_w): block reductions
    float pv[4];
    float lm = -INFINITY;
#pragma unroll
    for (int q = 0; q < 4; q++) { pv[q] = prior_w[q * 1024 + tid]; lm = fmaxf(lm, pv[q]); }
#pragma unroll
    for (int o = 32; o; o >>= 1) lm = fmaxf(lm, __shfl_xor(lm, o));
    if (lane == 0) red[wid] = lm;
    __syncthreads();
    float gm = red[0];
#pragma unroll
    for (int w = 1; w < 16; w++) gm = fmaxf(gm, red[w]);
    __syncthreads();
    float ls = 0.f;
#pragma unroll
    for (int q = 0; q < 4; q++) ls += __expf(pv[q] - gm);
#pragma unroll
    for (int o = 32; o; o >>= 1) ls += __shfl_xor(ls, o);
    if (lane == 0) red[wid] = ls;
    __syncthreads();
    float gs = 0.f;
#pragma unroll
    for (int w = 0; w < 16; w++) gs += red[w];
    float logZp = gm + __logf(gs);

    // step 0
#pragma unroll
    for (int q = 0; q < 4; q++) {
        int j = q * 1024 + tid;
        float sc = all_emis[(size_t)b * SS + j] + pv[q] - logZp;
        out[(size_t)b * SS + j] = sc;
        Sbuf[0][j] = sc;
    }
    __syncthreads();

    // steps 1..L-1
    int cur = 0;
    for (int t = 1; t < LL; t++) {
#pragma unroll
        for (int q = 0; q < 4; q++) {
            int j = q * 1024 + tid;
            float em = all_emis[((size_t)t * BB + b) * SS + j];
            float sk[7];
            float m = -INFINITY;
#pragma unroll
            for (int k = 0; k < 7; k++) {
                sk[k] = Sbuf[cur][dst[q][k]] + lw[q][k];
                m = fmaxf(m, sk[k]);
            }
            float sum = 0.f;
#pragma unroll
            for (int k = 0; k < 7; k++) sum += __expf(sk[k] - m);
            float val = (m == -INFINITY) ? -INFINITY : em + m + __logf(sum);
            out[((size_t)t * BB + b) * SS + j] = val;
            Sbuf[cur ^ 1][j] = val;
        }
        __syncthreads();
        cur ^= 1;
    }
}

extern "C" void kernel_launch(void* const* d_in, const int* in_sizes, int n_in,
                              void* d_out, int out_size, void* d_ws, size_t ws_size,
                              hipStream_t stream) {
    const int*   stories = (const int*)d_in[0];
    const float* trans_w = (const float*)d_in[2];
    const float* emis_w  = (const float*)d_in[3];
    const float* prior_w = (const float*)d_in[4];
    float* out = (float*)d_out;

    char* ws = (char*)d_ws;
    float* smT      = (float*)(ws);                                   // 32 MB
    float* all_emis = (float*)(ws + (size_t)VV * SS * 4);             // 4 MB
    float* logZ     = (float*)(ws + (size_t)VV * SS * 4 + (size_t)LL * BB * SS * 4);
    int*   g_dest   = (int*)  ((char*)logZ + SS * 4);
    float* g_lw     = (float*)((char*)g_dest + SS * 7 * 4);

    k_logZ<<<SS / 4, 256, 0, stream>>>(emis_w, logZ);
    k_trans<<<SS / 256, 256, 0, stream>>>(trans_w, g_dest, g_lw);
    k_smooth<<<dim3(ZD, VV / VC), 256, 0, stream>>>(emis_w, logZ, smT);
    k_emis<<<LL * BB, 256, 0, stream>>>(stories, smT, all_emis);
    k_forward<<<BB, 1024, 0, stream>>>(g_dest, g_lw, prior_w, all_emis, out);
}

// Round 2
// 165.810 us; speedup vs baseline: 1.2027x; 1.2027x over previous
//
#include <hip/hip_runtime.h>
#include <math.h>

#define XYD 16
#define ZD 16
#define SS 4096
#define VV 2048
#define BB 8
#define LL 32
#define WW 8
#define VC 32          // v-chunk for smoothing kernel
#define SM_STRIDE 257  // transposed LDS tile stride (states dim +1 pad)

#define GUARD_L 16
#define GUARD_R 512
#define EBUF_N (GUARD_L + SS + GUARD_R)  // 4624 floats per buffer

// ---------------- Kernel 1: logZ[s] = logsumexp over V of emis_w[s,:] ----------------
__global__ void k_logZ(const float* __restrict__ emis_w, float* __restrict__ logZ) {
    int wave = threadIdx.x >> 6;
    int lane = threadIdx.x & 63;
    int row  = blockIdx.x * 4 + wave;
    const float* r = emis_w + (size_t)row * VV;
    float vals[32];
    float m = -INFINITY;
#pragma unroll
    for (int k = 0; k < 8; k++) {
        float4 f = ((const float4*)r)[k * 64 + lane];
        vals[k*4+0] = f.x; vals[k*4+1] = f.y; vals[k*4+2] = f.z; vals[k*4+3] = f.w;
    }
#pragma unroll
    for (int k = 0; k < 32; k++) m = fmaxf(m, vals[k]);
#pragma unroll
    for (int o = 32; o; o >>= 1) m = fmaxf(m, __shfl_xor(m, o));
    float sum = 0.f;
#pragma unroll
    for (int k = 0; k < 32; k++) sum += __expf(vals[k] - m);
#pragma unroll
    for (int o = 32; o; o >>= 1) sum += __shfl_xor(sum, o);
    if (lane == 0) logZ[row] = m + __logf(sum);
}

// ---------------- Kernel 2: smoothing + transpose (float4 loads, transposed tile) ----
// smoothedT[v*S + s] = log( 0.2 * sum of 5 neighbor softmax-probs )
__global__ void k_smooth(const float* __restrict__ emis_w, const float* __restrict__ logZ,
                         float* __restrict__ smT) {
    __shared__ float tileT[VC * SM_STRIDE];  // [v][state], 32,896 B
    int z  = blockIdx.x;
    int v0 = blockIdx.y * VC;
    int tid = threadIdx.x;
    int rsub = tid >> 3;        // 0..31
    int c0   = (tid & 7) * 4;   // 0,4,..,28

#pragma unroll
    for (int it = 0; it < 8; it++) {
        int r  = it * 32 + rsub;         // plane state 0..255
        int sg = z * 256 + r;
        float lz = logZ[sg];
        float4 w = *(const float4*)(emis_w + (size_t)sg * VV + v0 + c0);
        tileT[(c0+0)*SM_STRIDE + r] = __expf(w.x - lz);
        tileT[(c0+1)*SM_STRIDE + r] = __expf(w.y - lz);
        tileT[(c0+2)*SM_STRIDE + r] = __expf(w.z - lz);
        tileT[(c0+3)*SM_STRIDE + r] = __expf(w.w - lz);
    }
    __syncthreads();

    int x = tid & 15, y = tid >> 4;
    int sxp = (x < 15) ? tid + 1  : tid;
    int sxm = (x > 0)  ? tid - 1  : tid;
    int syp = (y < 15) ? tid + 16 : tid;
    int sym = (y > 0)  ? tid - 16 : tid;
    float* o = smT + (size_t)v0 * SS + z * 256 + tid;
#pragma unroll
    for (int i = 0; i < VC; i++) {
        const float* tb = tileT + i * SM_STRIDE;
        float s = tb[tid] + tb[sxp] + tb[sxm] + tb[syp] + tb[sym];
        o[(size_t)i * SS] = __logf(s * 0.2f);
    }
}

// ---------------- Kernel 3: all_emis[t,b,s] = sum_w smoothedT[tok][s] (float4) -------
__global__ void k_emis(const int* __restrict__ stories, const float* __restrict__ smT,
                       float* __restrict__ all_emis) {
    int blk = blockIdx.x;
    int t = blk >> 3, b = blk & 7;
    int tid = threadIdx.x;
    int tok[WW];
#pragma unroll
    for (int w = 0; w < WW; w++) tok[w] = stories[(b * LL + t) * WW + w];
#pragma unroll
    for (int i = 0; i < 4; i++) {
        int s = i * 1024 + tid * 4;
        float4 acc = {0.f, 0.f, 0.f, 0.f};
#pragma unroll
        for (int w = 0; w < WW; w++) {
            if (tok[w] < VV) {  // wave-uniform
                float4 f = *(const float4*)(smT + (size_t)tok[w] * SS + s);
                acc.x += f.x; acc.y += f.y; acc.z += f.z; acc.w += f.w;
            }
        }
        *(float4*)(all_emis + ((size_t)t * BB + b) * SS + s) = acc;
    }
}

// ---------------- Kernel 4: transition tables (geometric order) ----------------------
// pw_geo[j*7+d] = exp(w_k(d) - m_j) for valid d (0 otherwise); am_tab[j] = -log(se_j)
// d: 0=self, 1=x+1, 2=x-1, 3=y+1, 4=y-1, 5=z+1, 6=z+2 (matches reference offs order)
__global__ void k_trans(const float* __restrict__ trans_w, float* __restrict__ pw_geo,
                        float* __restrict__ am_tab) {
    int j = blockIdx.x * 256 + threadIdx.x;
    int zz = j >> 8, rem = j & 255, yy = rem >> 4, xx = rem & 15;
    bool val[7];
    val[0] = true;
    val[1] = (xx < 15); val[2] = (xx > 0);
    val[3] = (yy < 15); val[4] = (yy > 0);
    val[5] = (zz < 15); val[6] = (zz < 14);
    float raw[7];
#pragma unroll
    for (int k = 0; k < 7; k++) raw[k] = trans_w[j * 7 + k];
    float w[7];
    int cnt = 0;
    float m = -INFINITY;
#pragma unroll
    for (int d = 0; d < 7; d++) {
        if (val[d]) { w[d] = raw[cnt++]; m = fmaxf(m, w[d]); }
    }
    float se = 0.f;
#pragma unroll
    for (int d = 0; d < 7; d++) if (val[d]) se += expf(w[d] - m);
#pragma unroll
    for (int d = 0; d < 7; d++) pw_geo[j * 7 + d] = val[d] ? expf(w[d] - m) : 0.f;
    am_tab[j] = -logf(se);
}

// ---------------- Kernel 5: forward recurrence (prob-space, b128 gathers) ------------
// one block per batch (8 blocks, 1024 threads, 4 consecutive states/thread)
__global__ void __launch_bounds__(1024) k_forward(
    const float* __restrict__ pw_geo, const float* __restrict__ am_tab,
    const float* __restrict__ prior_w, const float* __restrict__ all_emis,
    float* __restrict__ out) {
    __shared__ __align__(16) float Ebuf[2][EBUF_N];
    __shared__ __align__(16) float red[16];
    int b = blockIdx.x;
    int tid = threadIdx.x;
    int lane = tid & 63, wid = tid >> 6;

    // zero guard rings (read by boundary threads, always multiplied by pw=0)
    if (tid < GUARD_L) { Ebuf[0][tid] = 0.f; Ebuf[1][tid] = 0.f; }
    if (tid < GUARD_R) {
        Ebuf[0][GUARD_L + SS + tid] = 0.f;
        Ebuf[1][GUARD_L + SS + tid] = 0.f;
    }

    // per-thread transition weights, geometric order, states j0..j0+3
    union { float4 v4[7]; float f[28]; } U;
    {
        const float4* p4 = (const float4*)(pw_geo) + (size_t)tid * 7;
#pragma unroll
        for (int k = 0; k < 7; k++) U.v4[k] = p4[k];
    }
    float4 am4 = ((const float4*)am_tab)[tid];
    float4 pv  = ((const float4*)prior_w)[tid];

    // priors log-softmax denominator (block reduction)
    float lm = fmaxf(fmaxf(pv.x, pv.y), fmaxf(pv.z, pv.w));
#pragma unroll
    for (int o = 32; o; o >>= 1) lm = fmaxf(lm, __shfl_xor(lm, o));
    if (lane == 0) red[wid] = lm;
    __syncthreads();
    float gm = red[0];
#pragma unroll
    for (int w = 1; w < 16; w++) gm = fmaxf(gm, red[w]);
    __syncthreads();
    float ls = __expf(pv.x - gm) + __expf(pv.y - gm) + __expf(pv.z - gm) + __expf(pv.w - gm);
#pragma unroll
    for (int o = 32; o; o >>= 1) ls += __shfl_xor(ls, o);
    if (lane == 0) red[wid] = ls;
    __syncthreads();
    float gs = 0.f;
#pragma unroll
    for (int w = 0; w < 16; w++) gs += red[w];
    float logZp = gm + __logf(gs);
    __syncthreads();

    // ---- step 0 ----
    float4 em0 = ((const float4*)(all_emis + (size_t)b * SS))[tid];
    float v0 = em0.x + pv.x - logZp;
    float v1 = em0.y + pv.y - logZp;
    float v2 = em0.z + pv.z - logZp;
    float v3 = em0.w + pv.w - logZp;
    {
        float4 ov = {v0, v1, v2, v3};
        ((float4*)(out + (size_t)b * SS))[tid] = ov;
    }
    float m = fmaxf(fmaxf(v0, v1), fmaxf(v2, v3));
#pragma unroll
    for (int o = 32; o; o >>= 1) m = fmaxf(m, __shfl_xor(m, o));
    if (lane == 0) red[wid] = m;
    __syncthreads();
    float smax;
    {
        float4 r0 = ((const float4*)red)[0], r1 = ((const float4*)red)[1];
        float4 r2 = ((const float4*)red)[2], r3 = ((const float4*)red)[3];
        smax = fmaxf(fmaxf(fmaxf(r0.x, r0.y), fmaxf(r0.z, r0.w)),
               fmaxf(fmaxf(fmaxf(r1.x, r1.y), fmaxf(r1.z, r1.w)),
               fmaxf(fmaxf(fmaxf(r2.x, r2.y), fmaxf(r2.z, r2.w)),
                     fmaxf(fmaxf(r3.x, r3.y), fmaxf(r3.z, r3.w)))));
    }
    {
        float4 E = {__expf(v0 - smax), __expf(v1 - smax), __expf(v2 - smax), __expf(v3 - smax)};
        ((float4*)(Ebuf[0] + GUARD_L))[tid] = E;
    }
    __syncthreads();

    // ---- steps 1..L-1 ----
    int cur = 0;
    for (int t = 1; t < LL; t++) {
        const float4* Ep = (const float4*)(Ebuf[cur] + GUARD_L);
        float4 A  = Ep[tid];
        float4 Bx = Ep[tid + 1];
        float4 Cx = Ep[tid - 1];
        float4 Yp = Ep[tid + 4];
        float4 Ym = Ep[tid - 4];
        float4 Zp = Ep[tid + 64];
        float4 Zq = Ep[tid + 128];
        float4 em = ((const float4*)(all_emis + ((size_t)t * BB + b) * SS))[tid];

        float a0 = A.x*U.f[0]  + A.y*U.f[1]  + Cx.w*U.f[2]  + Yp.x*U.f[3]  + Ym.x*U.f[4]  + Zp.x*U.f[5]  + Zq.x*U.f[6];
        float a1 = A.y*U.f[7]  + A.z*U.f[8]  + A.x*U.f[9]   + Yp.y*U.f[10] + Ym.y*U.f[11] + Zp.y*U.f[12] + Zq.y*U.f[13];
        float a2 = A.z*U.f[14] + A.w*U.f[15] + A.y*U.f[16]  + Yp.z*U.f[17] + Ym.z*U.f[18] + Zp.z*U.f[19] + Zq.z*U.f[20];
        float a3 = A.w*U.f[21] + Bx.x*U.f[22]+ A.z*U.f[23]  + Yp.w*U.f[24] + Ym.w*U.f[25] + Zp.w*U.f[26] + Zq.w*U.f[27];

        v0 = em.x + __logf(a0) + smax + am4.x;
        v1 = em.y + __logf(a1) + smax + am4.y;
        v2 = em.z + __logf(a2) + smax + am4.z;
        v3 = em.w + __logf(a3) + smax + am4.w;

        {
            float4 ov = {v0, v1, v2, v3};
            ((float4*)(out + ((size_t)t * BB + b) * SS))[tid] = ov;
        }

        float mm = fmaxf(fmaxf(v0, v1), fmaxf(v2, v3));
#pragma unroll
        for (int o = 32; o; o >>= 1) mm = fmaxf(mm, __shfl_xor(mm, o));
        if (lane == 0) red[wid] = mm;
        __syncthreads();
        {
            float4 r0 = ((const float4*)red)[0], r1 = ((const float4*)red)[1];
            float4 r2 = ((const float4*)red)[2], r3 = ((const float4*)red)[3];
            smax = fmaxf(fmaxf(fmaxf(r0.x, r0.y), fmaxf(r0.z, r0.w)),
                   fmaxf(fmaxf(fmaxf(r1.x, r1.y), fmaxf(r1.z, r1.w)),
                   fmaxf(fmaxf(fmaxf(r2.x, r2.y), fmaxf(r2.z, r2.w)),
                         fmaxf(fmaxf(r3.x, r3.y), fmaxf(r3.z, r3.w)))));
        }
        {
            float4 E = {__expf(v0 - smax), __expf(v1 - smax), __expf(v2 - smax), __expf(v3 - smax)};
            ((float4*)(Ebuf[cur ^ 1] + GUARD_L))[tid] = E;
        }
        __syncthreads();
        cur ^= 1;
    }
}

extern "C" void kernel_launch(void* const* d_in, const int* in_sizes, int n_in,
                              void* d_out, int out_size, void* d_ws, size_t ws_size,
                              hipStream_t stream) {
    const int*   stories = (const int*)d_in[0];
    const float* trans_w = (const float*)d_in[2];
    const float* emis_w  = (const float*)d_in[3];
    const float* prior_w = (const float*)d_in[4];
    float* out = (float*)d_out;

    char* ws = (char*)d_ws;
    float* smT      = (float*)(ws);                                        // 32 MB
    float* all_emis = (float*)(ws + (size_t)VV * SS * 4);                  // 4 MB
    float* logZ     = (float*)(ws + (size_t)VV * SS * 4 + (size_t)LL * BB * SS * 4);  // 16 KB
    float* pw_geo   = (float*)((char*)logZ + SS * 4);                      // 112 KB
    float* am_tab   = (float*)((char*)pw_geo + (size_t)SS * 7 * 4);        // 16 KB

    k_logZ<<<SS / 4, 256, 0, stream>>>(emis_w, logZ);
    k_trans<<<SS / 256, 256, 0, stream>>>(trans_w, pw_geo, am_tab);
    k_smooth<<<dim3(ZD, VV / VC), 256, 0, stream>>>(emis_w, logZ, smT);
    k_emis<<<LL * BB, 256, 0, stream>>>(stories, smT, all_emis);
    k_forward<<<BB, 1024, 0, stream>>>(pw_geo, am_tab, prior_w, all_emis, out);
}